// Round 9
// baseline (8150.490 us; speedup 1.0000x reference)
//
#include <hip/hip_runtime.h>
#include <math.h>

#define D_DIM 256
#define KSEL  16
#define BQ    128
#define BN    128
#define DK    16
#define NT    13
#define CHUNK (NT * BN)          // 1664
#define LDP   132                // row stride (words): 132%32=4 -> bank spread

// LDS word offsets. Tile phase: xs[DK][LDP] | ys[DK][LDP] | sc[64][LDP].
// Merge phase reuses: md[256][17] @0 | mi[256][17] @4352 (after final barrier).
#define XS_OFF 0
#define YS_OFF (DK * LDP)                  // 2112
#define SC_OFF (2 * DK * LDP)              // 4224
#define SMEM_WORDS (SC_OFF + 64 * LDP)     // 12672 words = 50688 B -> 3 blocks/CU
#define MI_OFF 4352

__device__ __forceinline__ bool pair_less(float a, int ia, float b, int ib) {
    return (a < b) || (a == b && ia < ib);
}

// Branchless sorted insert (ascending); compile-time indices only (rule #20).
#define INSERT_CAND(sval, ival)                                              \
    do {                                                                     \
        _Pragma("unroll")                                                    \
        for (int jj = KSEL - 1; jj >= 1; --jj) {                             \
            bool cj  = pair_less((sval), (ival), bd[jj], bi[jj]);            \
            bool cj1 = pair_less((sval), (ival), bd[jj - 1], bi[jj - 1]);    \
            bd[jj] = cj ? (cj1 ? bd[jj - 1] : (sval)) : bd[jj];              \
            bi[jj] = cj ? (cj1 ? bi[jj - 1] : (ival)) : bi[jj];              \
        }                                                                    \
        if (pair_less((sval), (ival), bd[0], bi[0])) {                       \
            bd[0] = (sval); bi[0] = (ival);                                  \
        }                                                                    \
    } while (0)

// ---------------------------------------------------------------- y2 norms
__global__ __launch_bounds__(256) void knn_y2(const float* __restrict__ y,
                                              float* __restrict__ y2, int N) {
    int gw   = (blockIdx.x * 256 + threadIdx.x) >> 6;
    int lane = threadIdx.x & 63;
    if (gw >= N) return;
    const float4 v =
        *reinterpret_cast<const float4*>(y + (size_t)gw * D_DIM + lane * 4);
    float s = v.x * v.x + v.y * v.y + v.z * v.z + v.w * v.w;
#pragma unroll
    for (int off = 32; off > 0; off >>= 1) s += __shfl_down(s, off, 64);
    if (lane == 0) y2[gw] = s;
}

// ------------------------------------------- fused GEMM + per-chunk top-16
// 128x128 tile, 8x8 microtile (1 B LDS / FMA — R2's 4x4 was 2 B/FMA and
// LDS-pipe-bound at VALU 47%). Single-buffered staging (R4's reg-staged
// dbuf blew VGPR to 176 and halved occupancy). No min-waves clamp (R1).
__global__ __launch_bounds__(256) void knn_phase1(
    const float* __restrict__ x, const float* __restrict__ y,
    const float* __restrict__ y2, float* __restrict__ pd,
    int* __restrict__ pi, int N, int S) {
    __shared__ float smem[SMEM_WORDS];

    const int tid   = threadIdx.x;
    const int qbase = blockIdx.x * BQ;
    const int chunk = blockIdx.y;
    const int tq    = tid >> 4;       // 0..15: q micro-row (rows tq*8..+7)
    const int tn    = tid & 15;       // 0..15: n micro-col (cols tn*8..+7)
    const int srow  = tid >> 1;       // staging row 0..127
    const int sdh   = (tid & 1) * 8;  // staging d-offset 0/8
    const int sq    = tid >> 1;       // scan: query 0..127 (fixed per thread)
    const int spart = tid & 1;        // scan: 64-col half
    const int sql   = sq & 63;        // row within score half
    const int sqh   = sq >> 6;        // which score half this thread scans

    float bd[KSEL];
    int   bi[KSEL];
#pragma unroll
    for (int j = 0; j < KSEL; ++j) { bd[j] = __builtin_inff(); bi[j] = 0x7fffffff; }

    for (int t = 0; t < NT; ++t) {
        const int nbase = chunk * CHUNK + t * BN;

        float yv2[8];
#pragma unroll
        for (int j = 0; j < 8; ++j) {
            const int gn = nbase + tn * 8 + j;
            yv2[j] = (gn < N) ? y2[gn] : 0.0f;
        }

        float acc[8][8];
#pragma unroll
        for (int i = 0; i < 8; ++i)
#pragma unroll
            for (int j = 0; j < 8; ++j) acc[i][j] = 0.0f;

        for (int ks = 0; ks < D_DIM / DK; ++ks) {
            const int dk = ks * DK;
            __syncthreads();   // prev readers done before overwrite
            // stage x,y transposed: [d][row]. Write banks = (4*(sdh+i)+srow)%32
            // -> srow 0..31 spans all banks; sdh 0/8 aliases 2-way (free).
            {
                const float4 gx0 = *reinterpret_cast<const float4*>(
                    x + (size_t)(qbase + srow) * D_DIM + dk + sdh);
                const float4 gx1 = *reinterpret_cast<const float4*>(
                    x + (size_t)(qbase + srow) * D_DIM + dk + sdh + 4);
                float* xs = smem + XS_OFF;
                xs[(sdh + 0) * LDP + srow] = gx0.x;
                xs[(sdh + 1) * LDP + srow] = gx0.y;
                xs[(sdh + 2) * LDP + srow] = gx0.z;
                xs[(sdh + 3) * LDP + srow] = gx0.w;
                xs[(sdh + 4) * LDP + srow] = gx1.x;
                xs[(sdh + 5) * LDP + srow] = gx1.y;
                xs[(sdh + 6) * LDP + srow] = gx1.z;
                xs[(sdh + 7) * LDP + srow] = gx1.w;

                const int gn = nbase + srow;
                float4 gy0 = make_float4(0.f, 0.f, 0.f, 0.f), gy1 = gy0;
                if (gn < N) {
                    gy0 = *reinterpret_cast<const float4*>(
                        y + (size_t)gn * D_DIM + dk + sdh);
                    gy1 = *reinterpret_cast<const float4*>(
                        y + (size_t)gn * D_DIM + dk + sdh + 4);
                }
                float* ys = smem + YS_OFF;
                ys[(sdh + 0) * LDP + srow] = gy0.x;
                ys[(sdh + 1) * LDP + srow] = gy0.y;
                ys[(sdh + 2) * LDP + srow] = gy0.z;
                ys[(sdh + 3) * LDP + srow] = gy0.w;
                ys[(sdh + 4) * LDP + srow] = gy1.x;
                ys[(sdh + 5) * LDP + srow] = gy1.y;
                ys[(sdh + 6) * LDP + srow] = gy1.z;
                ys[(sdh + 7) * LDP + srow] = gy1.w;
            }
            __syncthreads();

#pragma unroll
            for (int d = 0; d < DK; ++d) {
                const float4 xa0 = *reinterpret_cast<const float4*>(
                    &smem[XS_OFF + d * LDP + tq * 8]);
                const float4 xa1 = *reinterpret_cast<const float4*>(
                    &smem[XS_OFF + d * LDP + tq * 8 + 4]);
                const float4 yb0 = *reinterpret_cast<const float4*>(
                    &smem[YS_OFF + d * LDP + tn * 8]);
                const float4 yb1 = *reinterpret_cast<const float4*>(
                    &smem[YS_OFF + d * LDP + tn * 8 + 4]);
                const float xv[8] = {xa0.x, xa0.y, xa0.z, xa0.w,
                                     xa1.x, xa1.y, xa1.z, xa1.w};
                const float yv[8] = {yb0.x, yb0.y, yb0.z, yb0.w,
                                     yb1.x, yb1.y, yb1.z, yb1.w};
#pragma unroll
                for (int i = 0; i < 8; ++i)
#pragma unroll
                    for (int j = 0; j < 8; ++j)
                        acc[i][j] = fmaf(xv[i], yv[j], acc[i][j]);
            }
        }

        // ---- score + scan, two 64-query halves (sc fits LDS @3 blocks/CU)
#pragma unroll 1
        for (int h = 0; h < 2; ++h) {
            if ((tq >> 3) == h) {      // waves 2h,2h+1 write (wave-uniform)
                float* sc = smem + SC_OFF;
                const int lr0 = (tq & 7) * 8;
#pragma unroll
                for (int i = 0; i < 8; ++i) {
                    float4 s0, s1;
                    s0.x = (nbase + tn * 8 + 0 < N) ? fmaf(-2.f, acc[i][0], yv2[0]) : __builtin_inff();
                    s0.y = (nbase + tn * 8 + 1 < N) ? fmaf(-2.f, acc[i][1], yv2[1]) : __builtin_inff();
                    s0.z = (nbase + tn * 8 + 2 < N) ? fmaf(-2.f, acc[i][2], yv2[2]) : __builtin_inff();
                    s0.w = (nbase + tn * 8 + 3 < N) ? fmaf(-2.f, acc[i][3], yv2[3]) : __builtin_inff();
                    s1.x = (nbase + tn * 8 + 4 < N) ? fmaf(-2.f, acc[i][4], yv2[4]) : __builtin_inff();
                    s1.y = (nbase + tn * 8 + 5 < N) ? fmaf(-2.f, acc[i][5], yv2[5]) : __builtin_inff();
                    s1.z = (nbase + tn * 8 + 6 < N) ? fmaf(-2.f, acc[i][6], yv2[6]) : __builtin_inff();
                    s1.w = (nbase + tn * 8 + 7 < N) ? fmaf(-2.f, acc[i][7], yv2[7]) : __builtin_inff();
                    *reinterpret_cast<float4*>(&sc[(lr0 + i) * LDP + tn * 8]) = s0;
                    *reinterpret_cast<float4*>(&sc[(lr0 + i) * LDP + tn * 8 + 4]) = s1;
                }
            }
            __syncthreads();
            if (sqh == h) {            // waves 2h,2h+1 scan their 64 queries
                const float* scrow = &smem[SC_OFF + sql * LDP];
#pragma unroll 1
                for (int s = 0; s < 64; ++s) {
                    // banks = (5*sql + s + spart) % 32 -> exact 2-way (free)
                    const int w   = (s + sql + spart) & 63;
                    const int col = spart * 64 + w;
                    const int gn  = nbase + col;
                    const float sval = scrow[col];
                    if (gn < N && sval <= bd[KSEL - 1]) {
                        INSERT_CAND(sval, gn);
                    }
                }
            }
            __syncthreads();
        }
    }

    // ---- merge the 2 col-half lists per query; write partials
    {
        float* md = smem;
        int*   mi = (int*)&smem[MI_OFF];
        const int lid = sq * 2 + spart;
#pragma unroll
        for (int j = 0; j < KSEL; ++j) {
            md[lid * 17 + j] = bd[j];
            mi[lid * 17 + j] = bi[j];
        }
        __syncthreads();
        if (tid < BQ) {
            const float* l0d = &md[(tid * 2) * 17];
            const int*   l0i = &mi[(tid * 2) * 17];
#pragma unroll
            for (int j = 0; j < KSEL; ++j) { bd[j] = l0d[j]; bi[j] = l0i[j]; }
            const float* l1d = &md[(tid * 2 + 1) * 17];
            const int*   l1i = &mi[(tid * 2 + 1) * 17];
#pragma unroll 1
            for (int j = 0; j < KSEL; ++j) {
                const float v  = l1d[j];
                const int   id = l1i[j];
                if (!pair_less(v, id, bd[KSEL - 1], bi[KSEL - 1])) break;
                INSERT_CAND(v, id);
            }
            const size_t base = ((size_t)(qbase + tid) * S + chunk) * KSEL;
#pragma unroll
            for (int j = 0; j < KSEL; ++j) {
                pd[base + j] = bd[j];
                pi[base + j] = bi[j];
            }
        }
    }
}

// --------------------------------------------------- merge partial top-16s
__global__ __launch_bounds__(256) void knn_phase2(const float* __restrict__ pd,
                                                  const int* __restrict__ pi,
                                                  int* __restrict__ out, int S,
                                                  int Qtot) {
    const int q = blockIdx.x * 256 + threadIdx.x;
    if (q >= Qtot) return;

    float bd[KSEL];
    int   bi[KSEL];
#pragma unroll
    for (int j = 0; j < KSEL; ++j) { bd[j] = __builtin_inff(); bi[j] = 0x7fffffff; }

#pragma unroll 1
    for (int c = 0; c < S; ++c) {
        const float* pdl = pd + ((size_t)q * S + c) * KSEL;
        const int*   pil = pi + ((size_t)q * S + c) * KSEL;
#pragma unroll 1
        for (int j = 0; j < KSEL; ++j) {
            const float v  = pdl[j];
            const int   id = pil[j];
            if (!pair_less(v, id, bd[KSEL - 1], bi[KSEL - 1])) break;
            INSERT_CAND(v, id);
        }
    }

#pragma unroll
    for (int j = 0; j < KSEL; ++j) out[q * KSEL + j] = bi[j];
}

extern "C" void kernel_launch(void* const* d_in, const int* in_sizes, int n_in,
                              void* d_out, int out_size, void* d_ws,
                              size_t ws_size, hipStream_t stream) {
    const float* x = (const float*)d_in[0];
    const float* y = (const float*)d_in[1];
    int* out = (int*)d_out;

    const int Q = in_sizes[0] / D_DIM;      // 2048
    const int N = in_sizes[1] / D_DIM;      // 100000
    const int S = (N + CHUNK - 1) / CHUNK;  // 61

    float* y2 = (float*)d_ws;
    float* pd = y2 + N;
    int*   pi = (int*)(pd + (size_t)Q * S * KSEL);

    knn_y2<<<(N * 64 + 255) / 256, 256, 0, stream>>>(y, y2, N);
    knn_phase1<<<dim3(Q / BQ, S), 256, 0, stream>>>(x, y, y2, pd, pi, N, S);
    knn_phase2<<<(Q + 255) / 256, 256, 0, stream>>>(pd, pi, out, S, Q);
}